// Round 1
// baseline (102.075 us; speedup 1.0000x reference)
//
#include <hip/hip_runtime.h>

#define S_DIM 4096
#define C_DIM 2048      // C1 == C2
#define N_DIM 1024
#define K_DIM 4096      // C1 + C2

typedef __attribute__((ext_vector_type(8))) short bf16x8;
typedef __attribute__((ext_vector_type(4))) float f32x4;

__device__ static inline unsigned short f2bf(float f) {
    unsigned int u = __float_as_uint(f);
    u += 0x7FFFu + ((u >> 16) & 1u);
    return (unsigned short)(u >> 16);
}

// ---------------- exp + cast to bf16 into workspace ----------------
// src is (rows x 2048) f32 row-major; dst is (rows x 4096) bf16 row-major,
// written at column offset dst_col_off.
__global__ void exp_cast_kernel(const float* __restrict__ src,
                                unsigned short* __restrict__ dst,
                                int dst_col_off, int total4) {
    int stride = gridDim.x * blockDim.x;
    for (int i = blockIdx.x * blockDim.x + threadIdx.x; i < total4; i += stride) {
        int e = i << 2;
        int r = e >> 11;          // src cols = 2048
        int c = e & 2047;
        const float4 v = *reinterpret_cast<const float4*>(src + e);
        ushort4 o;
        o.x = f2bf(__expf(v.x));
        o.y = f2bf(__expf(v.y));
        o.z = f2bf(__expf(v.z));
        o.w = f2bf(__expf(v.w));
        *reinterpret_cast<ushort4*>(dst + (((size_t)r << 12) + dst_col_off + c)) = o;
    }
}

// ---------------- per-node logsumexp over concat(w1,w2) ----------------
// one wave per node row
__global__ void logz_kernel(const float* __restrict__ w1,
                            const float* __restrict__ w2,
                            float* __restrict__ lz) {
    int n = blockIdx.x;
    int lane = threadIdx.x;   // 0..63
    const float* r1 = w1 + ((size_t)n << 11);
    const float* r2 = w2 + ((size_t)n << 11);
    float mx = -3.0e38f;
    for (int c = lane * 4; c < C_DIM; c += 256) {
        float4 v = *reinterpret_cast<const float4*>(r1 + c);
        mx = fmaxf(mx, fmaxf(fmaxf(v.x, v.y), fmaxf(v.z, v.w)));
        float4 u = *reinterpret_cast<const float4*>(r2 + c);
        mx = fmaxf(mx, fmaxf(fmaxf(u.x, u.y), fmaxf(u.z, u.w)));
    }
    #pragma unroll
    for (int off = 32; off > 0; off >>= 1) mx = fmaxf(mx, __shfl_xor(mx, off));
    float s = 0.f;
    for (int c = lane * 4; c < C_DIM; c += 256) {
        float4 v = *reinterpret_cast<const float4*>(r1 + c);
        s += __expf(v.x - mx) + __expf(v.y - mx) + __expf(v.z - mx) + __expf(v.w - mx);
        float4 u = *reinterpret_cast<const float4*>(r2 + c);
        s += __expf(u.x - mx) + __expf(u.y - mx) + __expf(u.z - mx) + __expf(u.w - mx);
    }
    #pragma unroll
    for (int off = 32; off > 0; off >>= 1) s += __shfl_xor(s, off);
    if (lane == 0) lz[n] = mx + __logf(s);
}

// ---------------- bf16 MFMA GEMM: C = A * B^T, epilogue log(C) - lz ----------------
#define BM 128
#define BN 64
#define BK 32

typedef const unsigned int __attribute__((address_space(1)))* gas_ptr;
typedef unsigned int __attribute__((address_space(3)))* las_ptr;

__device__ static inline void gload_lds16(const unsigned short* g, unsigned short* l) {
    __builtin_amdgcn_global_load_lds((gas_ptr)(const void*)g, (las_ptr)(void*)l, 16, 0, 0);
}

__global__ __launch_bounds__(256, 2) void gemm_log_kernel(
        const unsigned short* __restrict__ A,   // S x K, bf16 bits, row-major
        const unsigned short* __restrict__ B,   // N x K, bf16 bits, row-major
        const float* __restrict__ lz,
        float* __restrict__ out) {
    __shared__ __align__(16) unsigned short As[BM * BK];   // 8 KB
    __shared__ __align__(16) unsigned short Bs[BN * BK];   // 4 KB
    const int tid  = threadIdx.x;
    const int lane = tid & 63;
    const int wave = tid >> 6;
    const int wr = wave >> 1;       // 0..1  -> 64-row strip
    const int wc = wave & 1;        // 0..1  -> 32-col strip
    const int bm = blockIdx.x;      // 0..31
    const int bn = blockIdx.y;      // 0..15

    // ---- staging addresses (global_load_lds: LDS dest = uniform base + lane*16B) ----
    const int srow = lane >> 2;              // 0..15 rows within a wave's 16-row chunk
    const int scol = (lane & 3) * 8;         // element col within BK
    const unsigned short* a_src0 = A + ((size_t)(bm * BM + wave * 16 + srow) << 12) + scol;
    const unsigned short* a_src1 = a_src0 + ((size_t)64 << 12);
    const unsigned short* b_src  = B + ((size_t)(bn * BN + wave * 16 + srow) << 12) + scol;
    unsigned short* a_dst0 = As + wave * 512;          // bytes: wave*1024
    unsigned short* a_dst1 = As + 2048 + wave * 512;   // second 64 rows
    unsigned short* b_dst  = Bs + wave * 512;

    // ---- fragment read addresses ----
    const int lcol = lane & 15;     // row (A) / col (B) within 16x16 frag
    const int lk   = lane >> 4;     // k-group 0..3 (8 bf16 each)
    const unsigned short* a_rd = As + (wr * 64 + lcol) * BK + lk * 8;
    const unsigned short* b_rd = Bs + (wc * 32 + lcol) * BK + lk * 8;

    f32x4 acc[4][2] = {};

    for (int kt = 0; kt < K_DIM / BK; ++kt) {
        __syncthreads();                       // everyone done reading previous tile
        const int ko = kt * BK;
        gload_lds16(a_src0 + ko, a_dst0);
        gload_lds16(a_src1 + ko, a_dst1);
        gload_lds16(b_src + ko, b_dst);
        asm volatile("s_waitcnt vmcnt(0)" ::: "memory");
        __syncthreads();                       // staged data visible

        bf16x8 a[4], b[2];
        #pragma unroll
        for (int m = 0; m < 4; ++m)
            a[m] = *reinterpret_cast<const bf16x8*>(a_rd + m * 16 * BK);
        #pragma unroll
        for (int n = 0; n < 2; ++n)
            b[n] = *reinterpret_cast<const bf16x8*>(b_rd + n * 16 * BK);
        #pragma unroll
        for (int m = 0; m < 4; ++m)
            #pragma unroll
            for (int n = 0; n < 2; ++n)
                acc[m][n] = __builtin_amdgcn_mfma_f32_16x16x32_bf16(a[m], b[n], acc[m][n], 0, 0, 0);
    }

    // ---- epilogue: out = log(acc) - lz[col] ----
    // C/D layout (verified m89/m91): col = lane&15, row = (lane>>4)*4 + reg
    const int col_base = bn * BN + wc * 32;
    float lzv[2];
    #pragma unroll
    for (int n = 0; n < 2; ++n) lzv[n] = lz[col_base + n * 16 + lcol];
    #pragma unroll
    for (int m = 0; m < 4; ++m) {
        const int row0 = bm * BM + wr * 64 + m * 16 + lk * 4;
        #pragma unroll
        for (int n = 0; n < 2; ++n) {
            const int col = col_base + n * 16 + lcol;
            #pragma unroll
            for (int j = 0; j < 4; ++j) {
                out[(size_t)(row0 + j) * N_DIM + col] = __logf(acc[m][n][j]) - lzv[n];
            }
        }
    }
}

// ---------------- emergency fallback (no workspace) ----------------
__global__ void naive_kernel(const float* __restrict__ ll1, const float* __restrict__ ll2,
                             const float* __restrict__ w1, const float* __restrict__ w2,
                             float* __restrict__ out) {
    int idx = blockIdx.x * blockDim.x + threadIdx.x;
    if (idx >= S_DIM * N_DIM) return;
    int s = idx >> 10, n = idx & (N_DIM - 1);
    const float* a1 = ll1 + (size_t)s * C_DIM;
    const float* a2 = ll2 + (size_t)s * C_DIM;
    const float* b1 = w1 + (size_t)n * C_DIM;
    const float* b2 = w2 + (size_t)n * C_DIM;
    float mx = -3.0e38f;
    for (int c = 0; c < C_DIM; ++c) mx = fmaxf(mx, b1[c]);
    for (int c = 0; c < C_DIM; ++c) mx = fmaxf(mx, b2[c]);
    float zs = 0.f, acc = 0.f;
    for (int c = 0; c < C_DIM; ++c) { zs += __expf(b1[c] - mx); acc += __expf(a1[c] + b1[c]); }
    for (int c = 0; c < C_DIM; ++c) { zs += __expf(b2[c] - mx); acc += __expf(a2[c] + b2[c]); }
    out[idx] = __logf(acc) - (mx + __logf(zs));
}

extern "C" void kernel_launch(void* const* d_in, const int* in_sizes, int n_in,
                              void* d_out, int out_size, void* d_ws, size_t ws_size,
                              hipStream_t stream) {
    const float* ll1 = (const float*)d_in[0];
    const float* ll2 = (const float*)d_in[1];
    const float* w1  = (const float*)d_in[2];
    const float* w2  = (const float*)d_in[3];
    float* out = (float*)d_out;

    const size_t a_elems = (size_t)S_DIM * K_DIM;
    const size_t b_elems = (size_t)N_DIM * K_DIM;
    const size_t need = (a_elems + b_elems) * sizeof(unsigned short) + N_DIM * sizeof(float);
    if (ws_size < need) {
        naive_kernel<<<(S_DIM * N_DIM + 255) / 256, 256, 0, stream>>>(ll1, ll2, w1, w2, out);
        return;
    }
    unsigned short* Aws = (unsigned short*)d_ws;
    unsigned short* Bws = Aws + a_elems;
    float* lzws = (float*)(Bws + b_elems);

    exp_cast_kernel<<<2048, 256, 0, stream>>>(ll1, Aws, 0,     S_DIM * C_DIM / 4);
    exp_cast_kernel<<<2048, 256, 0, stream>>>(ll2, Aws, C_DIM, S_DIM * C_DIM / 4);
    exp_cast_kernel<<<1024, 256, 0, stream>>>(w1,  Bws, 0,     N_DIM * C_DIM / 4);
    exp_cast_kernel<<<1024, 256, 0, stream>>>(w2,  Bws, C_DIM, N_DIM * C_DIM / 4);
    logz_kernel<<<N_DIM, 64, 0, stream>>>(w1, w2, lzws);
    gemm_log_kernel<<<dim3(S_DIM / BM, N_DIM / BN), 256, 0, stream>>>(Aws, Bws, lzws, out);
}

// Round 2
// 82.903 us; speedup vs baseline: 1.2313x; 1.2313x over previous
//
#include <hip/hip_runtime.h>

#define S_DIM 4096
#define C_DIM 2048      // C1 == C2
#define N_DIM 1024
#define K_DIM 4096      // C1 + C2

#define BM 128
#define BN 128
#define BK 32
#define NT (K_DIM / BK)         // 128 K-steps
#define BUF_BYTES 16384         // A 8KB + B 8KB per buffer
#define NBUF 3

typedef __attribute__((ext_vector_type(8))) short bf16x8;
typedef __attribute__((ext_vector_type(4))) float f32x4;

__device__ static inline unsigned short f2bf(float f) {
    unsigned int u = __float_as_uint(f);
    u += 0x7FFFu + ((u >> 16) & 1u);
    return (unsigned short)(u >> 16);
}

// ---------------- exp + cast to bf16 for A (both ll sources, one launch) ----------------
__global__ void exp_ll_kernel(const float* __restrict__ ll1,
                              const float* __restrict__ ll2,
                              unsigned short* __restrict__ A) {
    const int total4 = S_DIM * C_DIM / 4;
    int stride = gridDim.x * blockDim.x;
    for (int i = blockIdx.x * blockDim.x + threadIdx.x; i < total4; i += stride) {
        int e = i << 2;
        int r = e >> 11;          // src cols = 2048
        int c = e & 2047;
        size_t dst = ((size_t)r << 12) + c;
        float4 v = *reinterpret_cast<const float4*>(ll1 + e);
        ushort4 o;
        o.x = f2bf(__expf(v.x)); o.y = f2bf(__expf(v.y));
        o.z = f2bf(__expf(v.z)); o.w = f2bf(__expf(v.w));
        *reinterpret_cast<ushort4*>(A + dst) = o;
        float4 u = *reinterpret_cast<const float4*>(ll2 + e);
        ushort4 p;
        p.x = f2bf(__expf(u.x)); p.y = f2bf(__expf(u.y));
        p.z = f2bf(__expf(u.z)); p.w = f2bf(__expf(u.w));
        *reinterpret_cast<ushort4*>(A + dst + C_DIM) = p;
    }
}

// ---------------- w: exp->B (bf16) AND per-row logsumexp, fused ----------------
// one block (256 threads) per node row; each thread holds 16 f32 in regs
__global__ void w_kernel(const float* __restrict__ w1,
                         const float* __restrict__ w2,
                         unsigned short* __restrict__ B,
                         float* __restrict__ lz) {
    const int n = blockIdx.x;
    const int tid = threadIdx.x;          // 0..255
    const int lane = tid & 63, wv = tid >> 6;
    const float* r1 = w1 + ((size_t)n << 11);
    const float* r2 = w2 + ((size_t)n << 11);
    float4 v0 = *reinterpret_cast<const float4*>(r1 + tid * 8);
    float4 v1 = *reinterpret_cast<const float4*>(r1 + tid * 8 + 4);
    float4 u0 = *reinterpret_cast<const float4*>(r2 + tid * 8);
    float4 u1 = *reinterpret_cast<const float4*>(r2 + tid * 8 + 4);

    float mx = fmaxf(fmaxf(fmaxf(v0.x, v0.y), fmaxf(v0.z, v0.w)),
                     fmaxf(fmaxf(v1.x, v1.y), fmaxf(v1.z, v1.w)));
    mx = fmaxf(mx, fmaxf(fmaxf(fmaxf(u0.x, u0.y), fmaxf(u0.z, u0.w)),
                          fmaxf(fmaxf(u1.x, u1.y), fmaxf(u1.z, u1.w))));
    #pragma unroll
    for (int off = 32; off > 0; off >>= 1) mx = fmaxf(mx, __shfl_xor(mx, off));
    __shared__ float red[4];
    if (lane == 0) red[wv] = mx;
    __syncthreads();
    mx = fmaxf(fmaxf(red[0], red[1]), fmaxf(red[2], red[3]));

    float s = __expf(v0.x - mx) + __expf(v0.y - mx) + __expf(v0.z - mx) + __expf(v0.w - mx)
            + __expf(v1.x - mx) + __expf(v1.y - mx) + __expf(v1.z - mx) + __expf(v1.w - mx)
            + __expf(u0.x - mx) + __expf(u0.y - mx) + __expf(u0.z - mx) + __expf(u0.w - mx)
            + __expf(u1.x - mx) + __expf(u1.y - mx) + __expf(u1.z - mx) + __expf(u1.w - mx);
    #pragma unroll
    for (int off = 32; off > 0; off >>= 1) s += __shfl_xor(s, off);
    __syncthreads();
    __shared__ float red2[4];
    if (lane == 0) red2[wv] = s;
    __syncthreads();
    if (tid == 0)
        lz[n] = mx + __logf(red2[0] + red2[1] + red2[2] + red2[3]);

    // write exp(w) as bf16 into B row (cols tid*8, and 2048 + tid*8)
    unsigned short* brow = B + ((size_t)n << 12);
    ushort4 o;
    o.x = f2bf(__expf(v0.x)); o.y = f2bf(__expf(v0.y));
    o.z = f2bf(__expf(v0.z)); o.w = f2bf(__expf(v0.w));
    *reinterpret_cast<ushort4*>(brow + tid * 8) = o;
    o.x = f2bf(__expf(v1.x)); o.y = f2bf(__expf(v1.y));
    o.z = f2bf(__expf(v1.z)); o.w = f2bf(__expf(v1.w));
    *reinterpret_cast<ushort4*>(brow + tid * 8 + 4) = o;
    o.x = f2bf(__expf(u0.x)); o.y = f2bf(__expf(u0.y));
    o.z = f2bf(__expf(u0.z)); o.w = f2bf(__expf(u0.w));
    *reinterpret_cast<ushort4*>(brow + C_DIM + tid * 8) = o;
    o.x = f2bf(__expf(u1.x)); o.y = f2bf(__expf(u1.y));
    o.z = f2bf(__expf(u1.z)); o.w = f2bf(__expf(u1.w));
    *reinterpret_cast<ushort4*>(brow + C_DIM + tid * 8 + 4) = o;
}

// ---------------- bf16 MFMA GEMM: C = A*B^T, log-epilogue, depth-3 pipeline ----------------
typedef const unsigned int __attribute__((address_space(1)))* gas_ptr;
typedef unsigned int __attribute__((address_space(3)))* las_ptr;

__global__ __launch_bounds__(256) void gemm_log_kernel(
        const unsigned short* __restrict__ A,   // S x K bf16, row-major
        const unsigned short* __restrict__ B,   // N x K bf16, row-major
        const float* __restrict__ lz,
        float* __restrict__ out) {
    __shared__ __align__(16) char lds[NBUF * BUF_BYTES];   // 48 KB
    const int tid  = threadIdx.x;
    const int l    = tid & 63;
    const int w    = tid >> 6;
    // XCD-friendly decode: blocks with same bid%8 (same XCD, assumed) share bn
    const int bn = blockIdx.x & 7;     // 8 col-panels; B-panel (1MB) stays in that XCD's L2
    const int bm = blockIdx.x >> 3;    // 32 row-panels
    const int wr = w >> 1, wc = w & 1; // wave owns 64x64 quadrant
    const int lcol = l & 15, lk = l >> 4;

    // ---- staging: pre-swizzled global source, linear LDS dest (rule #21) ----
    // LDS layout per tile: byte(row,kg) = row*64 + ((kg ^ ((row>>1)&3))<<4), kg = 16B chunk
    const int kg = (l & 3) ^ ((l >> 3) & 3);
    const unsigned short* sA[2]; const unsigned short* sB[2];
    int dA[2], dB[2];
    #pragma unroll
    for (int i = 0; i < 2; ++i) {
        const int s   = i * 4 + w;            // 0..7, 16-row slab
        const int row = s * 16 + (l >> 2);
        sA[i] = A + (size_t)(bm * BM + row) * K_DIM + kg * 8;
        sB[i] = B + (size_t)(bn * BN + row) * K_DIM + kg * 8;
        dA[i] = s * 1024;                     // linear byte offset, A part
        dB[i] = 8192 + s * 1024;              // B part
    }

    // ---- fragment read offsets (swizzled) ----
    const int swz = (lk ^ ((lcol >> 1) & 3)) << 4;
    int aoff[4], boff[4];
    #pragma unroll
    for (int m = 0; m < 4; ++m) {
        aoff[m] = (wr * 64 + m * 16 + lcol) * 64 + swz;
        boff[m] = 8192 + (wc * 64 + m * 16 + lcol) * 64 + swz;
    }

    f32x4 acc[4][4] = {};

#define GLOAD(src, off) __builtin_amdgcn_global_load_lds((gas_ptr)(const void*)(src), \
        (las_ptr)(void*)(lds + (off)), 16, 0, 0)
#define STAGE(kt, bufb) { const int _ko = (kt) * BK; const int _bo = (bufb) * BUF_BYTES; \
        GLOAD(sA[0] + _ko, _bo + dA[0]); GLOAD(sA[1] + _ko, _bo + dA[1]);               \
        GLOAD(sB[0] + _ko, _bo + dB[0]); GLOAD(sB[1] + _ko, _bo + dB[1]); }

    STAGE(0, 0);
    STAGE(1, 1);                               // 8 loads in flight per thread
    int bufi = 0, buf2 = 2;
    for (int t = 0; t < NT; ++t) {
        if (t == NT - 1) { asm volatile("s_waitcnt vmcnt(0)" ::: "memory"); }
        else             { asm volatile("s_waitcnt vmcnt(4)" ::: "memory"); }  // tile t landed
        __builtin_amdgcn_s_barrier();
        if (t + 2 < NT) STAGE(t + 2, buf2);    // overwrite buf read in iter t-1 (safe after barrier)

        const char* base = lds + bufi * BUF_BYTES;
        bf16x8 a[4], b[4];
        #pragma unroll
        for (int m = 0; m < 4; ++m) a[m] = *reinterpret_cast<const bf16x8*>(base + aoff[m]);
        #pragma unroll
        for (int n = 0; n < 4; ++n) b[n] = *reinterpret_cast<const bf16x8*>(base + boff[n]);
        #pragma unroll
        for (int m = 0; m < 4; ++m)
            #pragma unroll
            for (int n = 0; n < 4; ++n)
                acc[m][n] = __builtin_amdgcn_mfma_f32_16x16x32_bf16(a[m], b[n], acc[m][n], 0, 0, 0);

        bufi = (bufi == 2) ? 0 : bufi + 1;
        buf2 = (buf2 == 2) ? 0 : buf2 + 1;
    }
#undef STAGE
#undef GLOAD

    // ---- epilogue: out = log(acc) - lz[col]; C/D: col=lane&15, row=(lane>>4)*4+j ----
    const int col_base = bn * BN + wc * 64;
    float lzv[4];
    #pragma unroll
    for (int n = 0; n < 4; ++n) lzv[n] = lz[col_base + n * 16 + lcol];
    #pragma unroll
    for (int m = 0; m < 4; ++m) {
        const int row0 = bm * BM + wr * 64 + m * 16 + lk * 4;
        #pragma unroll
        for (int n = 0; n < 4; ++n) {
            const int col = col_base + n * 16 + lcol;
            #pragma unroll
            for (int j = 0; j < 4; ++j)
                out[(size_t)(row0 + j) * N_DIM + col] = __logf(acc[m][n][j]) - lzv[n];
        }
    }
}

// ---------------- emergency fallback (no workspace) ----------------
__global__ void naive_kernel(const float* __restrict__ ll1, const float* __restrict__ ll2,
                             const float* __restrict__ w1, const float* __restrict__ w2,
                             float* __restrict__ out) {
    int idx = blockIdx.x * blockDim.x + threadIdx.x;
    if (idx >= S_DIM * N_DIM) return;
    int s = idx >> 10, n = idx & (N_DIM - 1);
    const float* a1 = ll1 + (size_t)s * C_DIM;
    const float* a2 = ll2 + (size_t)s * C_DIM;
    const float* b1 = w1 + (size_t)n * C_DIM;
    const float* b2 = w2 + (size_t)n * C_DIM;
    float mx = -3.0e38f;
    for (int c = 0; c < C_DIM; ++c) mx = fmaxf(mx, b1[c]);
    for (int c = 0; c < C_DIM; ++c) mx = fmaxf(mx, b2[c]);
    float zs = 0.f, acc = 0.f;
    for (int c = 0; c < C_DIM; ++c) { zs += __expf(b1[c] - mx); acc += __expf(a1[c] + b1[c]); }
    for (int c = 0; c < C_DIM; ++c) { zs += __expf(b2[c] - mx); acc += __expf(a2[c] + b2[c]); }
    out[idx] = __logf(acc) - (mx + __logf(zs));
}

extern "C" void kernel_launch(void* const* d_in, const int* in_sizes, int n_in,
                              void* d_out, int out_size, void* d_ws, size_t ws_size,
                              hipStream_t stream) {
    const float* ll1 = (const float*)d_in[0];
    const float* ll2 = (const float*)d_in[1];
    const float* w1  = (const float*)d_in[2];
    const float* w2  = (const float*)d_in[3];
    float* out = (float*)d_out;

    const size_t a_elems = (size_t)S_DIM * K_DIM;
    const size_t b_elems = (size_t)N_DIM * K_DIM;
    const size_t need = (a_elems + b_elems) * sizeof(unsigned short) + N_DIM * sizeof(float);
    if (ws_size < need) {
        naive_kernel<<<(S_DIM * N_DIM + 255) / 256, 256, 0, stream>>>(ll1, ll2, w1, w2, out);
        return;
    }
    unsigned short* Aws = (unsigned short*)d_ws;
    unsigned short* Bws = Aws + a_elems;
    float* lzws = (float*)(Bws + b_elems);

    exp_ll_kernel<<<2048, 256, 0, stream>>>(ll1, ll2, Aws);
    w_kernel<<<N_DIM, 256, 0, stream>>>(w1, w2, Bws, lzws);
    gemm_log_kernel<<<S_DIM / BM * (N_DIM / BN), 256, 0, stream>>>(Aws, Bws, lzws, out);
}

// Round 3
// 82.291 us; speedup vs baseline: 1.2404x; 1.0074x over previous
//
#include <hip/hip_runtime.h>

#define S_DIM 4096
#define C_DIM 2048      // C1 == C2
#define N_DIM 1024
#define K_DIM 4096      // C1 + C2

#define BM 64
#define BN 128
#define BK 32
#define NT (K_DIM / BK)         // 128 K-steps
#define TILE_BYTES 12288        // (64 A rows + 128 B rows) * 64 B
#define NBUF 3

typedef __attribute__((ext_vector_type(8))) short bf16x8;
typedef __attribute__((ext_vector_type(4))) float f32x4;

__device__ static inline unsigned short f2bf(float f) {
    unsigned int u = __float_as_uint(f);
    u += 0x7FFFu + ((u >> 16) & 1u);
    return (unsigned short)(u >> 16);
}

// ---------------- exp + cast to bf16 for A (both ll sources, one launch) ----------------
__global__ void exp_ll_kernel(const float* __restrict__ ll1,
                              const float* __restrict__ ll2,
                              unsigned short* __restrict__ A) {
    const int total4 = S_DIM * C_DIM / 4;
    int stride = gridDim.x * blockDim.x;
    for (int i = blockIdx.x * blockDim.x + threadIdx.x; i < total4; i += stride) {
        int e = i << 2;
        int r = e >> 11;          // src cols = 2048
        int c = e & 2047;
        size_t dst = ((size_t)r << 12) + c;
        float4 v = *reinterpret_cast<const float4*>(ll1 + e);
        ushort4 o;
        o.x = f2bf(__expf(v.x)); o.y = f2bf(__expf(v.y));
        o.z = f2bf(__expf(v.z)); o.w = f2bf(__expf(v.w));
        *reinterpret_cast<ushort4*>(A + dst) = o;
        float4 u = *reinterpret_cast<const float4*>(ll2 + e);
        ushort4 p;
        p.x = f2bf(__expf(u.x)); p.y = f2bf(__expf(u.y));
        p.z = f2bf(__expf(u.z)); p.w = f2bf(__expf(u.w));
        *reinterpret_cast<ushort4*>(A + dst + C_DIM) = p;
    }
}

// ---------------- w: exp->B (bf16) AND per-row logsumexp, fused ----------------
__global__ void w_kernel(const float* __restrict__ w1,
                         const float* __restrict__ w2,
                         unsigned short* __restrict__ B,
                         float* __restrict__ lz) {
    const int n = blockIdx.x;
    const int tid = threadIdx.x;          // 0..255
    const int lane = tid & 63, wv = tid >> 6;
    const float* r1 = w1 + ((size_t)n << 11);
    const float* r2 = w2 + ((size_t)n << 11);
    float4 v0 = *reinterpret_cast<const float4*>(r1 + tid * 8);
    float4 v1 = *reinterpret_cast<const float4*>(r1 + tid * 8 + 4);
    float4 u0 = *reinterpret_cast<const float4*>(r2 + tid * 8);
    float4 u1 = *reinterpret_cast<const float4*>(r2 + tid * 8 + 4);

    float mx = fmaxf(fmaxf(fmaxf(v0.x, v0.y), fmaxf(v0.z, v0.w)),
                     fmaxf(fmaxf(v1.x, v1.y), fmaxf(v1.z, v1.w)));
    mx = fmaxf(mx, fmaxf(fmaxf(fmaxf(u0.x, u0.y), fmaxf(u0.z, u0.w)),
                          fmaxf(fmaxf(u1.x, u1.y), fmaxf(u1.z, u1.w))));
    #pragma unroll
    for (int off = 32; off > 0; off >>= 1) mx = fmaxf(mx, __shfl_xor(mx, off));
    __shared__ float red[4];
    if (lane == 0) red[wv] = mx;
    __syncthreads();
    mx = fmaxf(fmaxf(red[0], red[1]), fmaxf(red[2], red[3]));

    float s = __expf(v0.x - mx) + __expf(v0.y - mx) + __expf(v0.z - mx) + __expf(v0.w - mx)
            + __expf(v1.x - mx) + __expf(v1.y - mx) + __expf(v1.z - mx) + __expf(v1.w - mx)
            + __expf(u0.x - mx) + __expf(u0.y - mx) + __expf(u0.z - mx) + __expf(u0.w - mx)
            + __expf(u1.x - mx) + __expf(u1.y - mx) + __expf(u1.z - mx) + __expf(u1.w - mx);
    #pragma unroll
    for (int off = 32; off > 0; off >>= 1) s += __shfl_xor(s, off);
    __shared__ float red2[4];
    if (lane == 0) red2[wv] = s;
    __syncthreads();
    if (tid == 0)
        lz[n] = mx + __logf(red2[0] + red2[1] + red2[2] + red2[3]);

    unsigned short* brow = B + ((size_t)n << 12);
    ushort4 o;
    o.x = f2bf(__expf(v0.x)); o.y = f2bf(__expf(v0.y));
    o.z = f2bf(__expf(v0.z)); o.w = f2bf(__expf(v0.w));
    *reinterpret_cast<ushort4*>(brow + tid * 8) = o;
    o.x = f2bf(__expf(v1.x)); o.y = f2bf(__expf(v1.y));
    o.z = f2bf(__expf(v1.z)); o.w = f2bf(__expf(v1.w));
    *reinterpret_cast<ushort4*>(brow + tid * 8 + 4) = o;
    o.x = f2bf(__expf(u0.x)); o.y = f2bf(__expf(u0.y));
    o.z = f2bf(__expf(u0.z)); o.w = f2bf(__expf(u0.w));
    *reinterpret_cast<ushort4*>(brow + C_DIM + tid * 8) = o;
    o.x = f2bf(__expf(u1.x)); o.y = f2bf(__expf(u1.y));
    o.z = f2bf(__expf(u1.z)); o.w = f2bf(__expf(u1.w));
    *reinterpret_cast<ushort4*>(brow + C_DIM + tid * 8 + 4) = o;
}

// ---------------- bf16 MFMA GEMM: C = A*B^T, log-epilogue, depth-3 pipeline ----------------
typedef const unsigned int __attribute__((address_space(1)))* gas_ptr;
typedef unsigned int __attribute__((address_space(3)))* las_ptr;

__global__ __launch_bounds__(256) void gemm_log_kernel(
        const unsigned short* __restrict__ A,   // S x K bf16, row-major
        const unsigned short* __restrict__ B,   // N x K bf16, row-major
        const float* __restrict__ lz,
        float* __restrict__ out) {
    __shared__ __align__(16) char lds[NBUF * TILE_BYTES];   // 36 KB
    const int tid  = threadIdx.x;
    const int l    = tid & 63;
    const int w    = tid >> 6;
    const int bn = blockIdx.x & 7;     // XCD-affine: same-XCD blocks share the 1MB B-panel
    const int bm = blockIdx.x >> 3;    // 0..63
    const int wr = w & 1, wc = w >> 1; // wave owns 32(row) x 64(col)
    const int lcol = l & 15, lk = l >> 4;

    // ---- staging (rule #21): linear LDS dest, pre-swizzled global source ----
    // LDS tile: rows 0..63 = A (4KB), rows 64..191 = B; row stride 64B, 4 chunks of 16B.
    // chunk_lds c holds global chunk c ^ ((row>>1)&3).
    const int kg = (l & 3) ^ ((l >> 3) & 3);
    const unsigned short* src[3];
    int dst[3];
    #pragma unroll
    for (int g = 0; g < 3; ++g) {
        const int row = g * 64 + w * 16 + (l >> 2);
        src[g] = (g == 0)
            ? A + (size_t)(bm * BM + row) * K_DIM + kg * 8
            : B + (size_t)(bn * BN + row - 64) * K_DIM + kg * 8;
        dst[g] = row * 64 + (l & 3) * 16;      // == wave-uniform base + l*16
    }

    // ---- fragment read offsets (swizzled, loop-invariant) ----
    const int swz = (lk ^ ((lcol >> 1) & 3)) << 4;
    int aoff[2], boff[4];
    #pragma unroll
    for (int m = 0; m < 2; ++m) aoff[m] = (wr * 32 + m * 16 + lcol) * 64 + swz;
    #pragma unroll
    for (int n = 0; n < 4; ++n) boff[n] = 4096 + (wc * 64 + n * 16 + lcol) * 64 + swz;

    f32x4 acc[2][4] = {};

#define GLOAD(p, o) __builtin_amdgcn_global_load_lds((gas_ptr)(const void*)(p), \
        (las_ptr)(void*)(lds + (o)), 16, 0, 0)
#define STAGE(T, BUFB) { const int _ko = (T) * BK; const int _bo = (BUFB) * TILE_BYTES; \
        GLOAD(src[0] + _ko, _bo + dst[0]); GLOAD(src[1] + _ko, _bo + dst[1]);           \
        GLOAD(src[2] + _ko, _bo + dst[2]); }
#define BODY(T, BUF, BUFS, WAITN, DOSTAGE) {                                            \
        asm volatile("s_waitcnt vmcnt(" #WAITN ")" ::: "memory");                       \
        __builtin_amdgcn_s_barrier();                                                   \
        if (DOSTAGE) STAGE((T) + 2, BUFS);                                              \
        const char* base = lds + (BUF) * TILE_BYTES;                                    \
        bf16x8 a[2], b[4];                                                              \
        _Pragma("unroll") for (int m = 0; m < 2; ++m)                                   \
            a[m] = *reinterpret_cast<const bf16x8*>(base + aoff[m]);                    \
        _Pragma("unroll") for (int n = 0; n < 4; ++n)                                   \
            b[n] = *reinterpret_cast<const bf16x8*>(base + boff[n]);                    \
        _Pragma("unroll") for (int m = 0; m < 2; ++m)                                   \
            _Pragma("unroll") for (int n = 0; n < 4; ++n)                               \
                acc[m][n] = __builtin_amdgcn_mfma_f32_16x16x32_bf16(a[m], b[n],         \
                                                                   acc[m][n], 0, 0, 0); }

    STAGE(0, 0);
    STAGE(1, 1);                               // 6 loads in flight per thread
    for (int t3 = 0; t3 < NT - 2; t3 += 3) {   // 126 = 42*3 steps, compile-time buf idx
        BODY(t3 + 0, 0, 2, 3, 1);
        BODY(t3 + 1, 1, 0, 3, 1);
        BODY(t3 + 2, 2, 1, 3, 1);
    }
    BODY(NT - 2, 0, 2, 3, 0);                  // t=126: tile landed, nothing left to stage
    BODY(NT - 1, 1, 0, 0, 0);                  // t=127: drain
#undef BODY
#undef STAGE
#undef GLOAD

    // ---- epilogue: out = log(acc) - lz[col]; C/D: col=lane&15, row=(lane>>4)*4+j ----
    const int col_base = bn * BN + wc * 64;
    float lzv[4];
    #pragma unroll
    for (int n = 0; n < 4; ++n) lzv[n] = lz[col_base + n * 16 + lcol];
    #pragma unroll
    for (int m = 0; m < 2; ++m) {
        const int row0 = bm * BM + wr * 32 + m * 16 + lk * 4;
        #pragma unroll
        for (int n = 0; n < 4; ++n) {
            const int col = col_base + n * 16 + lcol;
            #pragma unroll
            for (int j = 0; j < 4; ++j)
                out[(size_t)(row0 + j) * N_DIM + col] = __logf(acc[m][n][j]) - lzv[n];
        }
    }
}

// ---------------- emergency fallback (no workspace) ----------------
__global__ void naive_kernel(const float* __restrict__ ll1, const float* __restrict__ ll2,
                             const float* __restrict__ w1, const float* __restrict__ w2,
                             float* __restrict__ out) {
    int idx = blockIdx.x * blockDim.x + threadIdx.x;
    if (idx >= S_DIM * N_DIM) return;
    int s = idx >> 10, n = idx & (N_DIM - 1);
    const float* a1 = ll1 + (size_t)s * C_DIM;
    const float* a2 = ll2 + (size_t)s * C_DIM;
    const float* b1 = w1 + (size_t)n * C_DIM;
    const float* b2 = w2 + (size_t)n * C_DIM;
    float mx = -3.0e38f;
    for (int c = 0; c < C_DIM; ++c) mx = fmaxf(mx, b1[c]);
    for (int c = 0; c < C_DIM; ++c) mx = fmaxf(mx, b2[c]);
    float zs = 0.f, acc = 0.f;
    for (int c = 0; c < C_DIM; ++c) { zs += __expf(b1[c] - mx); acc += __expf(a1[c] + b1[c]); }
    for (int c = 0; c < C_DIM; ++c) { zs += __expf(b2[c] - mx); acc += __expf(a2[c] + b2[c]); }
    out[idx] = __logf(acc) - (mx + __logf(zs));
}

extern "C" void kernel_launch(void* const* d_in, const int* in_sizes, int n_in,
                              void* d_out, int out_size, void* d_ws, size_t ws_size,
                              hipStream_t stream) {
    const float* ll1 = (const float*)d_in[0];
    const float* ll2 = (const float*)d_in[1];
    const float* w1  = (const float*)d_in[2];
    const float* w2  = (const float*)d_in[3];
    float* out = (float*)d_out;

    const size_t a_elems = (size_t)S_DIM * K_DIM;
    const size_t b_elems = (size_t)N_DIM * K_DIM;
    const size_t need = (a_elems + b_elems) * sizeof(unsigned short) + N_DIM * sizeof(float);
    if (ws_size < need) {
        naive_kernel<<<(S_DIM * N_DIM + 255) / 256, 256, 0, stream>>>(ll1, ll2, w1, w2, out);
        return;
    }
    unsigned short* Aws = (unsigned short*)d_ws;
    unsigned short* Bws = Aws + a_elems;
    float* lzws = (float*)(Bws + b_elems);

    exp_ll_kernel<<<2048, 256, 0, stream>>>(ll1, ll2, Aws);
    w_kernel<<<N_DIM, 256, 0, stream>>>(w1, w2, Bws, lzws);
    gemm_log_kernel<<<(S_DIM / BM) * (N_DIM / BN), 256, 0, stream>>>(Aws, Bws, lzws, out);
}

// Round 4
// 70.855 us; speedup vs baseline: 1.4406x; 1.1614x over previous
//
#include <hip/hip_runtime.h>

#define S_DIM 4096
#define C_DIM 2048      // C1 == C2
#define N_DIM 1024
#define K_DIM 4096      // C1 + C2

#define BM 128
#define BN 128
#define BK 32
#define NT (K_DIM / BK)         // 128 K-steps
#define TILE_BYTES 16384        // (128 A rows + 128 B rows) * 64 B
#define NBUF 8                  // 128 KB LDS, depth-6 prefetch

typedef __attribute__((ext_vector_type(8))) short bf16x8;
typedef __attribute__((ext_vector_type(4))) float f32x4;

__device__ static inline unsigned short f2bf(float f) {
    unsigned int u = __float_as_uint(f);
    u += 0x7FFFu + ((u >> 16) & 1u);
    return (unsigned short)(u >> 16);
}

// ---------------- exp + cast to bf16 for A (both ll sources, one launch) ----------------
__global__ void exp_ll_kernel(const float* __restrict__ ll1,
                              const float* __restrict__ ll2,
                              unsigned short* __restrict__ A) {
    const int total4 = S_DIM * C_DIM / 4;
    int stride = gridDim.x * blockDim.x;
    for (int i = blockIdx.x * blockDim.x + threadIdx.x; i < total4; i += stride) {
        int e = i << 2;
        int r = e >> 11;          // src cols = 2048
        int c = e & 2047;
        size_t dst = ((size_t)r << 12) + c;
        float4 v = *reinterpret_cast<const float4*>(ll1 + e);
        ushort4 o;
        o.x = f2bf(__expf(v.x)); o.y = f2bf(__expf(v.y));
        o.z = f2bf(__expf(v.z)); o.w = f2bf(__expf(v.w));
        *reinterpret_cast<ushort4*>(A + dst) = o;
        float4 u = *reinterpret_cast<const float4*>(ll2 + e);
        ushort4 p;
        p.x = f2bf(__expf(u.x)); p.y = f2bf(__expf(u.y));
        p.z = f2bf(__expf(u.z)); p.w = f2bf(__expf(u.w));
        *reinterpret_cast<ushort4*>(A + dst + C_DIM) = p;
    }
}

// ---------------- w: exp->B (bf16) AND per-row logsumexp, fused ----------------
__global__ void w_kernel(const float* __restrict__ w1,
                         const float* __restrict__ w2,
                         unsigned short* __restrict__ B,
                         float* __restrict__ lz) {
    const int n = blockIdx.x;
    const int tid = threadIdx.x;          // 0..255
    const int lane = tid & 63, wv = tid >> 6;
    const float* r1 = w1 + ((size_t)n << 11);
    const float* r2 = w2 + ((size_t)n << 11);
    float4 v0 = *reinterpret_cast<const float4*>(r1 + tid * 8);
    float4 v1 = *reinterpret_cast<const float4*>(r1 + tid * 8 + 4);
    float4 u0 = *reinterpret_cast<const float4*>(r2 + tid * 8);
    float4 u1 = *reinterpret_cast<const float4*>(r2 + tid * 8 + 4);

    float mx = fmaxf(fmaxf(fmaxf(v0.x, v0.y), fmaxf(v0.z, v0.w)),
                     fmaxf(fmaxf(v1.x, v1.y), fmaxf(v1.z, v1.w)));
    mx = fmaxf(mx, fmaxf(fmaxf(fmaxf(u0.x, u0.y), fmaxf(u0.z, u0.w)),
                          fmaxf(fmaxf(u1.x, u1.y), fmaxf(u1.z, u1.w))));
    #pragma unroll
    for (int off = 32; off > 0; off >>= 1) mx = fmaxf(mx, __shfl_xor(mx, off));
    __shared__ float red[4];
    if (lane == 0) red[wv] = mx;
    __syncthreads();
    mx = fmaxf(fmaxf(red[0], red[1]), fmaxf(red[2], red[3]));

    float s = __expf(v0.x - mx) + __expf(v0.y - mx) + __expf(v0.z - mx) + __expf(v0.w - mx)
            + __expf(v1.x - mx) + __expf(v1.y - mx) + __expf(v1.z - mx) + __expf(v1.w - mx)
            + __expf(u0.x - mx) + __expf(u0.y - mx) + __expf(u0.z - mx) + __expf(u0.w - mx)
            + __expf(u1.x - mx) + __expf(u1.y - mx) + __expf(u1.z - mx) + __expf(u1.w - mx);
    #pragma unroll
    for (int off = 32; off > 0; off >>= 1) s += __shfl_xor(s, off);
    __shared__ float red2[4];
    if (lane == 0) red2[wv] = s;
    __syncthreads();
    if (tid == 0)
        lz[n] = mx + __logf(red2[0] + red2[1] + red2[2] + red2[3]);

    unsigned short* brow = B + ((size_t)n << 12);
    ushort4 o;
    o.x = f2bf(__expf(v0.x)); o.y = f2bf(__expf(v0.y));
    o.z = f2bf(__expf(v0.z)); o.w = f2bf(__expf(v0.w));
    *reinterpret_cast<ushort4*>(brow + tid * 8) = o;
    o.x = f2bf(__expf(v1.x)); o.y = f2bf(__expf(v1.y));
    o.z = f2bf(__expf(v1.z)); o.w = f2bf(__expf(v1.w));
    *reinterpret_cast<ushort4*>(brow + tid * 8 + 4) = o;
    o.x = f2bf(__expf(u0.x)); o.y = f2bf(__expf(u0.y));
    o.z = f2bf(__expf(u0.z)); o.w = f2bf(__expf(u0.w));
    *reinterpret_cast<ushort4*>(brow + C_DIM + tid * 8) = o;
    o.x = f2bf(__expf(u1.x)); o.y = f2bf(__expf(u1.y));
    o.z = f2bf(__expf(u1.z)); o.w = f2bf(__expf(u1.w));
    *reinterpret_cast<ushort4*>(brow + C_DIM + tid * 8 + 4) = o;
}

// ---------------- bf16 MFMA GEMM: C = A*B^T, log-epilogue, depth-6 pipeline ----------------
typedef const unsigned int __attribute__((address_space(1)))* gas_ptr;
typedef unsigned int __attribute__((address_space(3)))* las_ptr;

__global__ __launch_bounds__(256, 1) void gemm_log_kernel(
        const unsigned short* __restrict__ A,   // S x K bf16, row-major
        const unsigned short* __restrict__ B,   // N x K bf16, row-major
        const float* __restrict__ lz,
        float* __restrict__ out) {
    __shared__ __align__(16) char lds[NBUF * TILE_BYTES];   // 128 KB
    const int tid  = threadIdx.x;
    const int l    = tid & 63;
    const int w    = tid >> 6;
    const int bn = blockIdx.x & 7;     // XCD-affine: same-XCD blocks share the 1MB B-panel
    const int bm = blockIdx.x >> 3;    // 0..31
    const int wr = w >> 1, wc = w & 1; // wave owns 64x64 quadrant (4x4 frags: 32 FLOP/LDS-byte)
    const int lcol = l & 15, lk = l >> 4;

    // ---- staging (rule #21): linear LDS dest, pre-swizzled global source ----
    // LDS tile: rows 0..127 = A (8KB), rows 128..255 = B (8KB); row = 64B, 4 x 16B chunks.
    // chunk_lds c holds global chunk c ^ ((row>>1)&3).
    const int kg = (l & 3) ^ ((l >> 3) & 3);
    const unsigned short* src[4];
    int dst[4];
    #pragma unroll
    for (int i = 0; i < 4; ++i) {
        const int ri  = w * 4 + i;             // 16-row slab 0..15
        const int row = ri * 16 + (l >> 2);    // local row 0..255
        src[i] = (ri < 8)
            ? A + (size_t)(bm * BM + row) * K_DIM + kg * 8
            : B + (size_t)(bn * BN + row - 128) * K_DIM + kg * 8;
        dst[i] = row * 64 + (l & 3) * 16;      // == wave-uniform base + l*16
    }

    // ---- fragment read offsets (swizzled, loop-invariant) ----
    const int swz = (lk ^ ((lcol >> 1) & 3)) << 4;
    int aoff[4], boff[4];
    #pragma unroll
    for (int m = 0; m < 4; ++m) aoff[m] = (wr * 64 + m * 16 + lcol) * 64 + swz;
    #pragma unroll
    for (int n = 0; n < 4; ++n) boff[n] = 8192 + (wc * 64 + n * 16 + lcol) * 64 + swz;

    f32x4 acc[4][4] = {};

#define GLOAD(p, o) __builtin_amdgcn_global_load_lds((gas_ptr)(const void*)(p), \
        (las_ptr)(void*)(lds + (o)), 16, 0, 0)
#define STAGE(T, BUFB) { const int _ko = (T) * BK; const int _bo = (BUFB) * TILE_BYTES; \
        GLOAD(src[0] + _ko, _bo + dst[0]); GLOAD(src[1] + _ko, _bo + dst[1]);           \
        GLOAD(src[2] + _ko, _bo + dst[2]); GLOAD(src[3] + _ko, _bo + dst[3]); }
#define BODY(T, BUF, SBUF, WAITN, DOSTAGE) {                                            \
        asm volatile("s_waitcnt vmcnt(" #WAITN ")" ::: "memory");                       \
        __builtin_amdgcn_s_barrier();                                                   \
        if (DOSTAGE) STAGE((T) + 6, SBUF);                                              \
        const char* base = lds + (BUF) * TILE_BYTES;                                    \
        bf16x8 a[4], b[4];                                                              \
        _Pragma("unroll") for (int m = 0; m < 4; ++m)                                   \
            a[m] = *reinterpret_cast<const bf16x8*>(base + aoff[m]);                    \
        _Pragma("unroll") for (int n = 0; n < 4; ++n)                                   \
            b[n] = *reinterpret_cast<const bf16x8*>(base + boff[n]);                    \
        _Pragma("unroll") for (int m = 0; m < 4; ++m)                                   \
            _Pragma("unroll") for (int n = 0; n < 4; ++n)                               \
                acc[m][n] = __builtin_amdgcn_mfma_f32_16x16x32_bf16(a[m], b[n],         \
                                                                   acc[m][n], 0, 0, 0); }

    STAGE(0, 0); STAGE(1, 1); STAGE(2, 2);
    STAGE(3, 3); STAGE(4, 4); STAGE(5, 5);     // depth-6: 24 loads in flight per thread
    for (int t8 = 0; t8 < NT - 8; t8 += 8) {   // compile-time buffer indices
        BODY(t8 + 0, 0, 6, 20, 1); BODY(t8 + 1, 1, 7, 20, 1);
        BODY(t8 + 2, 2, 0, 20, 1); BODY(t8 + 3, 3, 1, 20, 1);
        BODY(t8 + 4, 4, 2, 20, 1); BODY(t8 + 5, 5, 3, 20, 1);
        BODY(t8 + 6, 6, 4, 20, 1); BODY(t8 + 7, 7, 5, 20, 1);
    }
    BODY(NT - 8, 0, 6, 20, 1);                 // stages tile 126
    BODY(NT - 7, 1, 7, 20, 1);                 // stages tile 127 (last)
    BODY(NT - 6, 2, 0, 20, 0);
    BODY(NT - 5, 3, 0, 16, 0);
    BODY(NT - 4, 4, 0, 12, 0);
    BODY(NT - 3, 5, 0,  8, 0);
    BODY(NT - 2, 6, 0,  4, 0);
    BODY(NT - 1, 7, 0,  0, 0);
#undef BODY
#undef STAGE
#undef GLOAD

    // ---- epilogue: out = log(acc) - lz[col]; C/D: col=lane&15, row=(lane>>4)*4+j ----
    const int col_base = bn * BN + wc * 64;
    float lzv[4];
    #pragma unroll
    for (int n = 0; n < 4; ++n) lzv[n] = lz[col_base + n * 16 + lcol];
    #pragma unroll
    for (int m = 0; m < 4; ++m) {
        const int row0 = bm * BM + wr * 64 + m * 16 + lk * 4;
        #pragma unroll
        for (int n = 0; n < 4; ++n) {
            const int col = col_base + n * 16 + lcol;
            #pragma unroll
            for (int j = 0; j < 4; ++j)
                out[(size_t)(row0 + j) * N_DIM + col] = __logf(acc[m][n][j]) - lzv[n];
        }
    }
}

// ---------------- emergency fallback (no workspace) ----------------
__global__ void naive_kernel(const float* __restrict__ ll1, const float* __restrict__ ll2,
                             const float* __restrict__ w1, const float* __restrict__ w2,
                             float* __restrict__ out) {
    int idx = blockIdx.x * blockDim.x + threadIdx.x;
    if (idx >= S_DIM * N_DIM) return;
    int s = idx >> 10, n = idx & (N_DIM - 1);
    const float* a1 = ll1 + (size_t)s * C_DIM;
    const float* a2 = ll2 + (size_t)s * C_DIM;
    const float* b1 = w1 + (size_t)n * C_DIM;
    const float* b2 = w2 + (size_t)n * C_DIM;
    float mx = -3.0e38f;
    for (int c = 0; c < C_DIM; ++c) mx = fmaxf(mx, b1[c]);
    for (int c = 0; c < C_DIM; ++c) mx = fmaxf(mx, b2[c]);
    float zs = 0.f, acc = 0.f;
    for (int c = 0; c < C_DIM; ++c) { zs += __expf(b1[c] - mx); acc += __expf(a1[c] + b1[c]); }
    for (int c = 0; c < C_DIM; ++c) { zs += __expf(b2[c] - mx); acc += __expf(a2[c] + b2[c]); }
    out[idx] = __logf(acc) - (mx + __logf(zs));
}

extern "C" void kernel_launch(void* const* d_in, const int* in_sizes, int n_in,
                              void* d_out, int out_size, void* d_ws, size_t ws_size,
                              hipStream_t stream) {
    const float* ll1 = (const float*)d_in[0];
    const float* ll2 = (const float*)d_in[1];
    const float* w1  = (const float*)d_in[2];
    const float* w2  = (const float*)d_in[3];
    float* out = (float*)d_out;

    const size_t a_elems = (size_t)S_DIM * K_DIM;
    const size_t b_elems = (size_t)N_DIM * K_DIM;
    const size_t need = (a_elems + b_elems) * sizeof(unsigned short) + N_DIM * sizeof(float);
    if (ws_size < need) {
        naive_kernel<<<(S_DIM * N_DIM + 255) / 256, 256, 0, stream>>>(ll1, ll2, w1, w2, out);
        return;
    }
    unsigned short* Aws = (unsigned short*)d_ws;
    unsigned short* Bws = Aws + a_elems;
    float* lzws = (float*)(Bws + b_elems);

    exp_ll_kernel<<<2048, 256, 0, stream>>>(ll1, ll2, Aws);
    w_kernel<<<N_DIM, 256, 0, stream>>>(w1, w2, Bws, lzws);
    gemm_log_kernel<<<(S_DIM / BM) * (N_DIM / BN), 256, 0, stream>>>(Aws, Bws, lzws, out);
}